// Round 9
// baseline (10474.843 us; speedup 1.0000x reference)
//
#include <hip/hip_runtime.h>

// Kernel ridge regression, RBF kernel. N=M=8192, D=32, gamma=1/32, reg=1e-3.
// R9: persistent kernel (plain launch) running all 128 CG iterations +
// predict, with a software global barrier (atomic counter + generation,
// agent-scope acquire/release). Co-residency guaranteed: 256 blocks x 512
// threads = 1 block/CU (LDS 33KB, VGPR<=256 via launch_bounds). Each block
// keeps its 256-col B-slice (bf16 hi/lo MFMA frags) in LDS for the whole
// solve; A-row frags live in registers. Exp factored: K = 2^{nxA} * 2^{dot}
// * 2^{bu}; col factor folded into staged weights, row factor applied once
// per row. NITER=128 (R5: 80 iters failed at 0.070 — do not cut).

#define NN 8192
#define DD 32
#define REGL 1e-3f
#define NITER 128
#define NBLK 256
#define NC2 (-0.045084220027780106f)  // -gamma*log2e
#define SCF (0.3002806023f)           // sqrt(2*gamma*log2e)

typedef short v8s __attribute__((ext_vector_type(8)));
typedef float v4f __attribute__((ext_vector_type(4)));

__device__ __forceinline__ float fast_exp2(float x) {
#if __has_builtin(__builtin_amdgcn_exp2f)
  return __builtin_amdgcn_exp2f(x);
#else
  float r;
  asm("v_exp_f32 %0, %1" : "=v"(r) : "v"(x));
  return r;
#endif
}

__device__ __forceinline__ ushort f2bf(float x) {  // RNE float->bf16 bits
  unsigned u = __float_as_uint(x);
  return (ushort)((u + 0x7fff + ((u >> 16) & 1)) >> 16);
}
__device__ __forceinline__ float bf2f(ushort b) {
  return __uint_as_float(((unsigned)b) << 16);
}

__device__ __forceinline__ double bfly64_d(double v) {
#pragma unroll
  for (int m = 1; m < 64; m <<= 1) v += __shfl_xor(v, m, 64);
  return v;
}
__device__ __forceinline__ double wave_down_sum_d(double v) {
#pragma unroll
  for (int off = 32; off > 0; off >>= 1) v += __shfl_down(v, off, 64);
  return v;
}
__device__ __forceinline__ double slot_sum32(const double* __restrict__ s,
                                             int lane) {
  double v = s[lane & 31];
#pragma unroll
  for (int m = 1; m < 32; m <<= 1) v += __shfl_xor(v, m, 64);
  return v;
}

// ---- software global barrier (sense via generation counter) ----
// bar[0] = arrival count, bar[1] = generation. Safe for reuse: count is
// reset by the last arriver BEFORE the release-store bumps the generation.
__device__ __forceinline__ void gbarrier(unsigned* bar) {
  __syncthreads();
  if (threadIdx.x == 0) {
    unsigned g =
        __hip_atomic_load(&bar[1], __ATOMIC_RELAXED, __HIP_MEMORY_SCOPE_AGENT);
    unsigned a = __hip_atomic_fetch_add(&bar[0], 1u, __ATOMIC_ACQ_REL,
                                        __HIP_MEMORY_SCOPE_AGENT);
    if (a == NBLK - 1) {
      __hip_atomic_store(&bar[0], 0u, __ATOMIC_RELAXED,
                         __HIP_MEMORY_SCOPE_AGENT);
      __hip_atomic_store(&bar[1], g + 1, __ATOMIC_RELEASE,
                         __HIP_MEMORY_SCOPE_AGENT);
    } else {
      unsigned tries = 0;
      while (__hip_atomic_load(&bar[1], __ATOMIC_ACQUIRE,
                               __HIP_MEMORY_SCOPE_AGENT) == g) {
        __builtin_amdgcn_s_sleep(2);
        if (++tries > (1u << 22)) break;  // escape hatch: fail, don't hang
      }
    }
  }
  __syncthreads();
}

// hi/lo bf16 fragment from global X: lane holds row `row`, k = kb..kb+7.
__device__ __forceinline__ void conv_frag(const float* __restrict__ X, int row,
                                          int kb, v8s& h, v8s& l) {
  const float4* rp = (const float4*)(X + (size_t)row * DD + kb);
  float4 f0 = rp[0], f1 = rp[1];
  float f[8] = {f0.x, f0.y, f0.z, f0.w, f1.x, f1.y, f1.z, f1.w};
  union {
    v8s v;
    ushort u[8];
  } H, L;
#pragma unroll
  for (int j = 0; j < 8; ++j) {
    float fs = SCF * f[j];
    ushort hb = f2bf(fs);
    H.u[j] = hb;
    L.u[j] = f2bf(fs - bf2f(hb));
  }
  h = H.v;
  l = L.v;
}

// ---------------- setup kernels ----------------

__global__ void setup_zero(float* __restrict__ q, float* __restrict__ out,
                           double* __restrict__ slots, int nsl,
                           unsigned* __restrict__ bar) {
  int i = blockIdx.x * 256 + threadIdx.x;
  if (i < NN) {
    q[i] = 0.f;
    out[i] = 0.f;
  }
  int st = gridDim.x * 256;
  for (int k = i; k < nsl; k += st) slots[k] = 0.0;
  if (i == 0) {
    bar[0] = 0u;
    bar[1] = 0u;
  }
}

// stores NC2 * ||x||^2
__global__ void row_norms(const float* __restrict__ X, float* __restrict__ xx) {
  int i = blockIdx.x * blockDim.x + threadIdx.x;
  if (i < NN) {
    const float4* row = (const float4*)(X + (size_t)i * DD);
    float s = 0.f;
#pragma unroll
    for (int k = 0; k < DD / 4; ++k) {
      float4 v = row[k];
      s += v.x * v.x + v.y * v.y + v.z * v.z + v.w * v.w;
    }
    xx[i] = NC2 * s;
  }
}

__global__ __launch_bounds__(256) void cg_init(const float* __restrict__ y,
                                               float* __restrict__ x,
                                               float* __restrict__ r,
                                               float* __restrict__ p,
                                               double* __restrict__ rho0,
                                               double* __restrict__ pp0) {
  int i = blockIdx.x * 256 + threadIdx.x;
  float v = y[i];
  x[i] = 0.f;
  r[i] = v;
  p[i] = v;
  __shared__ double sred[4];
  double acc = wave_down_sum_d((double)v * (double)v);
  if ((threadIdx.x & 63) == 0) sred[threadIdx.x >> 6] = acc;
  __syncthreads();
  if (threadIdx.x == 0) {
    double t = sred[0] + sred[1] + sred[2] + sred[3];
    rho0[blockIdx.x] = t;
    pp0[blockIdx.x] = t;
  }
}

// ---------------- matvec compute core ----------------
// racc[rs][u] += sum over this block's 256 cols of 2^{dot} * Wj'.
__device__ __forceinline__ void mv_compute(const v8s* ah, const v8s* al,
                                           const ushort (*Bh)[512],
                                           const ushort (*Bl)[512],
                                           const float* Wj, int lane,
                                           float racc[8][4]) {
  const int n = lane & 15;
  for (int t = 0; t < 16; ++t) {
    v8s bh = *(const v8s*)&Bh[t][lane * 8];
    v8s bl = *(const v8s*)&Bl[t][lane * 8];
    float wn = Wj[t * 16 + n];
#pragma unroll
    for (int rs = 0; rs < 8; ++rs) {
      v4f c = {0.f, 0.f, 0.f, 0.f};
      c = __builtin_amdgcn_mfma_f32_16x16x32_bf16(al[rs], bh, c, 0, 0, 0);
      c = __builtin_amdgcn_mfma_f32_16x16x32_bf16(ah[rs], bl, c, 0, 0, 0);
      c = __builtin_amdgcn_mfma_f32_16x16x32_bf16(ah[rs], bh, c, 0, 0, 0);
#pragma unroll
      for (int u = 0; u < 4; ++u)
        racc[rs][u] = fmaf(fast_exp2(c[u]), wn, racc[rs][u]);
    }
  }
}

// ---------------- persistent CG kernel ----------------
// Grid 256 blocks x 512 threads: 8 rowblocks (1024 rows) x 32 slices
// (256 cols). Exactly 1 block/CU (LDS 33KB, VGPR<=256 via bounds).

__global__ __launch_bounds__(512, 2) void cg_persist(
    const float* __restrict__ Xtr, const float* __restrict__ Xte,
    const float* __restrict__ xx_tr, const float* __restrict__ xx_te,
    float* __restrict__ xv, float* __restrict__ rv, float* __restrict__ p0,
    float* __restrict__ p1, float* __restrict__ q, double* __restrict__ rho,
    double* __restrict__ pqs, double* __restrict__ pps,
    unsigned* __restrict__ bar, float* __restrict__ out) {
  __shared__ __align__(16) ushort Bh[16][512];  // 16 col-tiles, hi plane
  __shared__ __align__(16) ushort Bl[16][512];  // lo plane
  __shared__ float Wj[256];
  __shared__ double sred[8];

  const int tid = threadIdx.x;
  const int lane = tid & 63;
  const int wid = tid >> 6;  // 0..7
  const int n = lane & 15, q4 = lane >> 4;
  const int rbi = blockIdx.x & 7;   // rowblock: 1024 rows
  const int sli = blockIdx.x >> 3;  // slice: 256 cols
  const int i0 = rbi * 1024 + wid * 128;
  const int jbase = sli * 256;

  // ---- stage B-slice into LDS once (frag layout, scaled, hi/lo) ----
  {
    int c = tid & 255;
    int j = jbase + c;
    const float4* rp = (const float4*)(Xtr + (size_t)j * DD);
    int g0 = (tid >> 8) * 2;
    int tile = c >> 4, cl = c & 15;
#pragma unroll
    for (int gg = 0; gg < 2; ++gg) {
      int g = g0 + gg;
      float4 f0 = rp[2 * g], f1 = rp[2 * g + 1];
      float f[8] = {f0.x, f0.y, f0.z, f0.w, f1.x, f1.y, f1.z, f1.w};
      union {
        ushort u[8];
        uint4 qq;
      } H, L;
#pragma unroll
      for (int e = 0; e < 8; ++e) {
        float fs = SCF * f[e];
        ushort hb = f2bf(fs);
        H.u[e] = hb;
        L.u[e] = f2bf(fs - bf2f(hb));
      }
      int ln = cl + 16 * g;
      *(uint4*)&Bh[tile][ln * 8] = H.qq;
      *(uint4*)&Bl[tile][ln * 8] = L.qq;
    }
  }
  __syncthreads();

  // ---- A fragments (128 rows per wave) in registers, converted once ----
  v8s ah[8], al[8];
#pragma unroll
  for (int rs = 0; rs < 8; ++rs)
    conv_frag(Xtr, i0 + rs * 16 + n, q4 * 8, ah[rs], al[rs]);

  for (int it = 0; it < NITER; ++it) {
    float* pcur = (it & 1) ? p1 : p0;
    float* poth = (it & 1) ? p0 : p1;
    const int first = (it == 0);
    float beta = 0.f;
    if (!first) {
      double r1 = slot_sum32(rho + (size_t)it * 32, lane);
      double r0 = slot_sum32(rho + (size_t)(it - 1) * 32, lane);
      beta = (float)(r1 / r0);
    }
    if (tid < 256) {  // stage weights: Wj' = p_j * 2^{NC2*||xb_j||^2}
      int j = jbase + tid;
      float wvv = first ? pcur[j] : fmaf(beta, poth[j], rv[j]);
      Wj[tid] = wvv * fast_exp2(xx_tr[j]);
    }
    if (sli == 0 && !first) {  // blocks 0..7: persist p_new + p.p partials
      double cpp = 0.0;
#pragma unroll
      for (int k2 = 0; k2 < 2; ++k2) {
        int row = rbi * 1024 + k2 * 512 + tid;
        float pn = fmaf(beta, poth[row], rv[row]);
        pcur[row] = pn;
        cpp += (double)pn * (double)pn;
      }
      double wsum = wave_down_sum_d(cpp);
      if (lane == 0) sred[wid] = wsum;
      __syncthreads();
      if (tid == 0) {
        double t = 0.0;
#pragma unroll
        for (int k3 = 0; k3 < 8; ++k3) t += sred[k3];
        atomicAdd(&pps[(size_t)it * 32 + rbi], t);
      }
    }
    __syncthreads();  // Wj ready (and sred safe for reuse)

    float racc[8][4] = {};
    mv_compute(ah, al, Bh, Bl, Wj, lane, racc);

    // reduce each row over the 16 col-lanes (C/D layout: col = lane&15)
#pragma unroll
    for (int rs = 0; rs < 8; ++rs)
#pragma unroll
      for (int u = 0; u < 4; ++u) {
#pragma unroll
        for (int m = 1; m < 16; m <<= 1)
          racc[rs][u] += __shfl_xor(racc[rs][u], m, 64);
      }
    double cpq = 0.0;
    if (n == 0) {
#pragma unroll
      for (int rs = 0; rs < 8; ++rs)
#pragma unroll
        for (int u = 0; u < 4; ++u) {
          int row = i0 + rs * 16 + q4 * 4 + u;
          float qc = racc[rs][u] * fast_exp2(xx_tr[row]);  // 2^{nxA}
          atomicAdd(&q[row], qc);
          float pnr = first ? pcur[row] : fmaf(beta, poth[row], rv[row]);
          cpq += (double)qc * (double)pnr;
        }
    }
    cpq = bfly64_d(cpq);
    if (lane == 0)
      atomicAdd(&pqs[(size_t)it * 32 + ((blockIdx.x * 8 + wid) & 31)], cpq);
    gbarrier(bar);  // q complete

    // ---- phase B: vector update on 16 blocks ----
    if (blockIdx.x < 16) {
      double rr = slot_sum32(rho + (size_t)it * 32, lane);
      double pqv = slot_sum32(pqs + (size_t)it * 32, lane);
      double ppv = slot_sum32(pps + (size_t)it * 32, lane);
      float alpha = (float)(rr / (pqv + (double)REGL * ppv));
      int i = blockIdx.x * 512 + tid;
      float pi = pcur[i];
      float qvv = q[i] + REGL * pi;
      xv[i] = fmaf(alpha, pi, xv[i]);
      float rn = fmaf(-alpha, qvv, rv[i]);
      rv[i] = rn;
      q[i] = 0.f;  // re-zero for next iteration's atomics
      double rsum = wave_down_sum_d((double)rn * (double)rn);
      if (lane == 0) sred[wid] = rsum;
      __syncthreads();
      if (tid == 0) {
        double t = 0.0;
#pragma unroll
        for (int k3 = 0; k3 < 8; ++k3) t += sred[k3];
        rho[(size_t)(it + 1) * 32 + blockIdx.x] = t;
      }
    }
    gbarrier(bar);  // x, r, rho, q-zero complete
  }

  // ---- predict: out = K_test @ alpha, same B-slice in LDS ----
  {
    v8s th[8], tl[8];
#pragma unroll
    for (int rs = 0; rs < 8; ++rs)
      conv_frag(Xte, i0 + rs * 16 + n, q4 * 8, th[rs], tl[rs]);
    if (tid < 256) {
      int j = jbase + tid;
      Wj[tid] = xv[j] * fast_exp2(xx_tr[j]);
    }
    __syncthreads();
    float racc[8][4] = {};
    mv_compute(th, tl, Bh, Bl, Wj, lane, racc);
#pragma unroll
    for (int rs = 0; rs < 8; ++rs)
#pragma unroll
      for (int u = 0; u < 4; ++u) {
#pragma unroll
        for (int m = 1; m < 16; m <<= 1)
          racc[rs][u] += __shfl_xor(racc[rs][u], m, 64);
      }
    if (n == 0) {
#pragma unroll
      for (int rs = 0; rs < 8; ++rs)
#pragma unroll
        for (int u = 0; u < 4; ++u) {
          int row = i0 + rs * 16 + q4 * 4 + u;
          atomicAdd(&out[row], racc[rs][u] * fast_exp2(xx_te[row]));
        }
    }
  }
}

// ---------------- launcher ----------------

extern "C" void kernel_launch(void* const* d_in, const int* in_sizes, int n_in,
                              void* d_out, int out_size, void* d_ws,
                              size_t ws_size, hipStream_t stream) {
  const float* X_train = (const float*)d_in[0];
  const float* y_train = (const float*)d_in[1];
  const float* X_test = (const float*)d_in[2];
  float* out = (float*)d_out;

  char* w = (char*)d_ws;
  size_t off = 0;
  float* xx_tr = (float*)(w + off); off += NN * 4;
  float* xx_te = (float*)(w + off); off += NN * 4;
  float* xv = (float*)(w + off); off += NN * 4;
  float* rv = (float*)(w + off); off += NN * 4;
  float* p0 = (float*)(w + off); off += NN * 4;
  float* p1 = (float*)(w + off); off += NN * 4;
  float* qv = (float*)(w + off); off += NN * 4;
  off = (off + 255) & ~(size_t)255;
  double* rho = (double*)(w + off); off += (size_t)(NITER + 1) * 32 * 8;
  double* pqs = (double*)(w + off); off += (size_t)NITER * 32 * 8;
  double* pps = (double*)(w + off); off += (size_t)(NITER + 1) * 32 * 8;
  unsigned* bar = (unsigned*)(w + off); off += 64;
  const int nslots = (3 * NITER + 2) * 32;
  if (ws_size < off) return;  // ~324KB; proven available since R3

  setup_zero<<<32, 256, 0, stream>>>(qv, out, rho, nslots, bar);
  row_norms<<<NN / 256, 256, 0, stream>>>(X_train, xx_tr);
  row_norms<<<NN / 256, 256, 0, stream>>>(X_test, xx_te);
  cg_init<<<NN / 256, 256, 0, stream>>>(y_train, xv, rv, p0, rho, pps);

  cg_persist<<<NBLK, 512, 0, stream>>>(X_train, X_test, xx_tr, xx_te, xv, rv,
                                       p0, p1, qv, rho, pqs, pps, bar, out);
}

// Round 10
// 8452.079 us; speedup vs baseline: 1.2393x; 1.2393x over previous
//
#include <hip/hip_runtime.h>

// Kernel ridge regression, RBF kernel. N=M=8192, D=32, gamma=1/32, reg=1e-3.
// R10: persistent kernel, software barrier made HIERARCHICAL (16 padded
// group counters -> root -> generation; flat 256-RMW-one-line barrier was
// ~32us — R9 counters: MfmaUtil 6%, VALUBusy 9%, i.e. 90% sync stall).
// 1024 thr/block (16 waves/CU, occupancy 2x), block-reduced p.Kp partials
// (2048->256 atomics/iter), phase B distributed across all blocks (32
// owned elements each; owners maintain p, x, pp locally).
// B-slice (256 cols, bf16 hi/lo MFMA frags) lives in LDS all 128 iters;
// A-row frags in registers. Exp factored: K = 2^nxA * 2^dot * 2^bu.
// NITER=128 (R5: 80 iters failed at 0.070 — do not cut).

#define NN 8192
#define DD 32
#define REGL 1e-3f
#define NITER 128
#define NBLK 256
#define NC2 (-0.045084220027780106f)  // -gamma*log2e
#define SCF (0.3002806023f)           // sqrt(2*gamma*log2e)

typedef short v8s __attribute__((ext_vector_type(8)));
typedef float v4f __attribute__((ext_vector_type(4)));

__device__ __forceinline__ float fast_exp2(float x) {
#if __has_builtin(__builtin_amdgcn_exp2f)
  return __builtin_amdgcn_exp2f(x);
#else
  float r;
  asm("v_exp_f32 %0, %1" : "=v"(r) : "v"(x));
  return r;
#endif
}

__device__ __forceinline__ ushort f2bf(float x) {  // RNE float->bf16 bits
  unsigned u = __float_as_uint(x);
  return (ushort)((u + 0x7fff + ((u >> 16) & 1)) >> 16);
}
__device__ __forceinline__ float bf2f(ushort b) {
  return __uint_as_float(((unsigned)b) << 16);
}

__device__ __forceinline__ double bfly64_d(double v) {
#pragma unroll
  for (int m = 1; m < 64; m <<= 1) v += __shfl_xor(v, m, 64);
  return v;
}
__device__ __forceinline__ double bfly32_d(double v) {
#pragma unroll
  for (int m = 1; m < 32; m <<= 1) v += __shfl_xor(v, m, 64);
  return v;
}
__device__ __forceinline__ double wave_down_sum_d(double v) {
#pragma unroll
  for (int off = 32; off > 0; off >>= 1) v += __shfl_down(v, off, 64);
  return v;
}
__device__ __forceinline__ double slot_sum32(const double* __restrict__ s,
                                             int lane) {
  double v = s[lane & 31];
#pragma unroll
  for (int m = 1; m < 32; m <<= 1) v += __shfl_xor(v, m, 64);
  return v;
}

// ---- hierarchical global barrier ----
// bar layout (uints): [0..255] 16 group counters, stride 16 (64B lines);
// [256] root counter; [272] generation. Reset by last root arriver before
// the release-store on generation.
__device__ __forceinline__ void gbarrier(unsigned* bar) {
  __syncthreads();
  if (threadIdx.x == 0) {
    unsigned* gen = bar + 272;
    unsigned g =
        __hip_atomic_load(gen, __ATOMIC_RELAXED, __HIP_MEMORY_SCOPE_AGENT);
    unsigned a =
        __hip_atomic_fetch_add(&bar[(blockIdx.x >> 4) * 16], 1u,
                               __ATOMIC_ACQ_REL, __HIP_MEMORY_SCOPE_AGENT);
    bool done = false;
    if (a == 15u) {
      unsigned ra = __hip_atomic_fetch_add(bar + 256, 1u, __ATOMIC_ACQ_REL,
                                           __HIP_MEMORY_SCOPE_AGENT);
      if (ra == 15u) {
#pragma unroll
        for (int k = 0; k < 16; ++k)
          __hip_atomic_store(&bar[k * 16], 0u, __ATOMIC_RELAXED,
                             __HIP_MEMORY_SCOPE_AGENT);
        __hip_atomic_store(bar + 256, 0u, __ATOMIC_RELAXED,
                           __HIP_MEMORY_SCOPE_AGENT);
        __hip_atomic_store(gen, g + 1, __ATOMIC_RELEASE,
                           __HIP_MEMORY_SCOPE_AGENT);
        done = true;
      }
    }
    if (!done) {
      unsigned tries = 0;
      while (__hip_atomic_load(gen, __ATOMIC_ACQUIRE,
                               __HIP_MEMORY_SCOPE_AGENT) == g) {
        __builtin_amdgcn_s_sleep(1);
        if (++tries > (1u << 22)) break;  // escape hatch: fail, don't hang
      }
    }
  }
  __syncthreads();
}

// hi/lo bf16 fragment from global X: lane holds row `row`, k = kb..kb+7.
__device__ __forceinline__ void conv_frag(const float* __restrict__ X, int row,
                                          int kb, v8s& h, v8s& l) {
  const float4* rp = (const float4*)(X + (size_t)row * DD + kb);
  float4 f0 = rp[0], f1 = rp[1];
  float f[8] = {f0.x, f0.y, f0.z, f0.w, f1.x, f1.y, f1.z, f1.w};
  union {
    v8s v;
    ushort u[8];
  } H, L;
#pragma unroll
  for (int j = 0; j < 8; ++j) {
    float fs = SCF * f[j];
    ushort hb = f2bf(fs);
    H.u[j] = hb;
    L.u[j] = f2bf(fs - bf2f(hb));
  }
  h = H.v;
  l = L.v;
}

// ---------------- setup kernels ----------------

__global__ void setup_zero(float* __restrict__ q, float* __restrict__ out,
                           double* __restrict__ slots, int nsl,
                           unsigned* __restrict__ bar) {
  int i = blockIdx.x * 256 + threadIdx.x;
  if (i < NN) {
    q[i] = 0.f;
    out[i] = 0.f;
  }
  int st = gridDim.x * 256;
  for (int k = i; k < nsl; k += st) slots[k] = 0.0;
  if (i < 512) bar[i] = 0u;
}

// stores NC2 * ||x||^2
__global__ void row_norms(const float* __restrict__ X, float* __restrict__ xx) {
  int i = blockIdx.x * blockDim.x + threadIdx.x;
  if (i < NN) {
    const float4* row = (const float4*)(X + (size_t)i * DD);
    float s = 0.f;
#pragma unroll
    for (int k = 0; k < DD / 4; ++k) {
      float4 v = row[k];
      s += v.x * v.x + v.y * v.y + v.z * v.z + v.w * v.w;
    }
    xx[i] = NC2 * s;
  }
}

__global__ __launch_bounds__(256) void cg_init(const float* __restrict__ y,
                                               float* __restrict__ x,
                                               float* __restrict__ r,
                                               float* __restrict__ p,
                                               double* __restrict__ rho0,
                                               double* __restrict__ pp0) {
  int i = blockIdx.x * 256 + threadIdx.x;
  float v = y[i];
  x[i] = 0.f;
  r[i] = v;
  p[i] = v;
  __shared__ double sred[4];
  double acc = wave_down_sum_d((double)v * (double)v);
  if ((threadIdx.x & 63) == 0) sred[threadIdx.x >> 6] = acc;
  __syncthreads();
  if (threadIdx.x == 0) {
    double t = sred[0] + sred[1] + sred[2] + sred[3];
    rho0[blockIdx.x] = t;
    pp0[blockIdx.x] = t;
  }
}

// ---------------- matvec compute core (4 row-tiles / wave) ----------------
__device__ __forceinline__ void mv_compute(const v8s* ah, const v8s* al,
                                           const ushort (*Bh)[512],
                                           const ushort (*Bl)[512],
                                           const float* Wj, int lane,
                                           float racc[4][4]) {
  const int n = lane & 15;
  for (int t = 0; t < 16; ++t) {
    v8s bh = *(const v8s*)&Bh[t][lane * 8];
    v8s bl = *(const v8s*)&Bl[t][lane * 8];
    float wn = Wj[t * 16 + n];
#pragma unroll
    for (int rs = 0; rs < 4; ++rs) {
      v4f c = {0.f, 0.f, 0.f, 0.f};
      c = __builtin_amdgcn_mfma_f32_16x16x32_bf16(al[rs], bh, c, 0, 0, 0);
      c = __builtin_amdgcn_mfma_f32_16x16x32_bf16(ah[rs], bl, c, 0, 0, 0);
      c = __builtin_amdgcn_mfma_f32_16x16x32_bf16(ah[rs], bh, c, 0, 0, 0);
#pragma unroll
      for (int u = 0; u < 4; ++u)
        racc[rs][u] = fmaf(fast_exp2(c[u]), wn, racc[rs][u]);
    }
  }
}

// ---------------- persistent CG kernel ----------------
// Grid 256 blocks x 1024 threads (16 waves): 8 rowblocks (1024 rows) x 32
// slices (256 cols). 1 block/CU; each block owns elements [32b,32b+32).

__global__ __launch_bounds__(1024, 4) void cg_persist(
    const float* __restrict__ Xtr, const float* __restrict__ Xte,
    const float* __restrict__ xx_tr, const float* __restrict__ xx_te,
    float* __restrict__ xv, float* __restrict__ rv, float* __restrict__ p0,
    float* __restrict__ p1, float* __restrict__ q, double* __restrict__ rho,
    double* __restrict__ pqs, double* __restrict__ pps,
    unsigned* __restrict__ bar, float* __restrict__ out) {
  __shared__ __align__(16) ushort Bh[16][512];  // 16 col-tiles, hi plane
  __shared__ __align__(16) ushort Bl[16][512];  // lo plane
  __shared__ float Wj[256];
  __shared__ double sredq[16];

  const int tid = threadIdx.x;
  const int lane = tid & 63;
  const int wid = tid >> 6;  // 0..15
  const int n = lane & 15, q4 = lane >> 4;
  const int rbi = blockIdx.x & 7;   // rowblock: 1024 rows
  const int sli = blockIdx.x >> 3;  // slice: 256 cols
  const int i0 = rbi * 1024 + wid * 64;  // 64 rows per wave
  const int jbase = sli * 256;
  const int iown = blockIdx.x * 32 + (tid & 31);  // owned element (tid<32)

  // ---- stage B-slice into LDS once (frag layout, scaled, hi/lo) ----
  {
    int c = tid & 255;
    int j = jbase + c;
    int g = tid >> 8;  // 0..3
    int tile = c >> 4, cl = c & 15;
    const float4* rp = (const float4*)(Xtr + (size_t)j * DD);
    float4 f0 = rp[2 * g], f1 = rp[2 * g + 1];
    float f[8] = {f0.x, f0.y, f0.z, f0.w, f1.x, f1.y, f1.z, f1.w};
    union {
      ushort u[8];
      uint4 qq;
    } H, L;
#pragma unroll
    for (int e = 0; e < 8; ++e) {
      float fs = SCF * f[e];
      ushort hb = f2bf(fs);
      H.u[e] = hb;
      L.u[e] = f2bf(fs - bf2f(hb));
    }
    int ln = cl + 16 * g;
    *(uint4*)&Bh[tile][ln * 8] = H.qq;
    *(uint4*)&Bl[tile][ln * 8] = L.qq;
  }

  // ---- A fragments (64 rows per wave) in registers, converted once ----
  v8s ah[4], al[4];
#pragma unroll
  for (int rs = 0; rs < 4; ++rs)
    conv_frag(Xtr, i0 + rs * 16 + n, q4 * 8, ah[rs], al[rs]);
  __syncthreads();

  for (int it = 0; it < NITER; ++it) {
    float* pcur = (it & 1) ? p1 : p0;
    float* poth = (it & 1) ? p0 : p1;
    const int first = (it == 0);
    double rho_k = slot_sum32(rho + (size_t)it * 32, lane);
    float beta = 0.f;
    if (!first) {
      double r0 = slot_sum32(rho + (size_t)(it - 1) * 32, lane);
      beta = (float)(rho_k / r0);
    }

    // owners: materialize p_k for owned elems + p.p partial
    float pown = 0.f;
    if (tid < 32) {
      if (first) {
        pown = pcur[iown];
      } else {
        pown = fmaf(beta, poth[iown], rv[iown]);
        pcur[iown] = pown;
        double c = bfly32_d((double)pown * (double)pown);
        if (tid == 0)
          atomicAdd(&pps[(size_t)it * 32 + (blockIdx.x & 31)], c);
      }
    }
    // stage weights: Wj' = p_j * 2^{NC2*||xb_j||^2}
    if (tid < 256) {
      int j = jbase + tid;
      float pj = first ? pcur[j] : fmaf(beta, poth[j], rv[j]);
      Wj[tid] = pj * fast_exp2(xx_tr[j]);
    }
    __syncthreads();

    float racc[4][4] = {};
    mv_compute(ah, al, Bh, Bl, Wj, lane, racc);

    // reduce each row over the 16 col-lanes (C/D layout: col = lane&15)
#pragma unroll
    for (int rs = 0; rs < 4; ++rs)
#pragma unroll
      for (int u = 0; u < 4; ++u) {
#pragma unroll
        for (int m = 1; m < 16; m <<= 1)
          racc[rs][u] += __shfl_xor(racc[rs][u], m, 64);
      }
    double cpq = 0.0;
    if (n == 0) {
#pragma unroll
      for (int rs = 0; rs < 4; ++rs)
#pragma unroll
        for (int u = 0; u < 4; ++u) {
          int row = i0 + rs * 16 + q4 * 4 + u;
          float qc = racc[rs][u] * fast_exp2(xx_tr[row]);  // 2^{nxA}
          atomicAdd(&q[row], qc);
          float pnr = first ? pcur[row] : fmaf(beta, poth[row], rv[row]);
          cpq += (double)qc * (double)pnr;
        }
    }
    // block-level p.Kp reduction -> single atomic per block
    cpq = bfly64_d(cpq);
    if (lane == 0) sredq[wid] = cpq;
    __syncthreads();
    if (tid == 0) {
      double t = 0.0;
#pragma unroll
      for (int k3 = 0; k3 < 16; ++k3) t += sredq[k3];
      atomicAdd(&pqs[(size_t)it * 32 + (blockIdx.x & 31)], t);
    }
    gbarrier(bar);  // q, pq, pp complete

    // ---- phase B (distributed): each block updates its 32 owned elems ----
    if (tid < 32) {
      double pqv = slot_sum32(pqs + (size_t)it * 32, lane);
      double ppv = slot_sum32(pps + (size_t)it * 32, lane);
      float alpha = (float)(rho_k / (pqv + (double)REGL * ppv));
      float sV = q[iown];
      xv[iown] = fmaf(alpha, pown, xv[iown]);
      float rn = rv[iown] - alpha * (sV + REGL * pown);
      rv[iown] = rn;
      q[iown] = 0.f;  // re-zero for next iteration's atomics
      double c = bfly32_d((double)rn * (double)rn);
      if (tid == 0)
        atomicAdd(&rho[(size_t)(it + 1) * 32 + (blockIdx.x & 31)], c);
    }
    gbarrier(bar);  // x, r, rho, q-zero complete
  }

  // ---- predict: out = K_test @ alpha, same B-slice in LDS ----
  {
    v8s th[4], tl[4];
#pragma unroll
    for (int rs = 0; rs < 4; ++rs)
      conv_frag(Xte, i0 + rs * 16 + n, q4 * 8, th[rs], tl[rs]);
    if (tid < 256) {
      int j = jbase + tid;
      Wj[tid] = xv[j] * fast_exp2(xx_tr[j]);
    }
    __syncthreads();
    float racc[4][4] = {};
    mv_compute(th, tl, Bh, Bl, Wj, lane, racc);
#pragma unroll
    for (int rs = 0; rs < 4; ++rs)
#pragma unroll
      for (int u = 0; u < 4; ++u) {
#pragma unroll
        for (int m = 1; m < 16; m <<= 1)
          racc[rs][u] += __shfl_xor(racc[rs][u], m, 64);
      }
    if (n == 0) {
#pragma unroll
      for (int rs = 0; rs < 4; ++rs)
#pragma unroll
        for (int u = 0; u < 4; ++u) {
          int row = i0 + rs * 16 + q4 * 4 + u;
          atomicAdd(&out[row], racc[rs][u] * fast_exp2(xx_te[row]));
        }
    }
  }
}

// ---------------- launcher ----------------

extern "C" void kernel_launch(void* const* d_in, const int* in_sizes, int n_in,
                              void* d_out, int out_size, void* d_ws,
                              size_t ws_size, hipStream_t stream) {
  const float* X_train = (const float*)d_in[0];
  const float* y_train = (const float*)d_in[1];
  const float* X_test = (const float*)d_in[2];
  float* out = (float*)d_out;

  char* w = (char*)d_ws;
  size_t off = 0;
  float* xx_tr = (float*)(w + off); off += NN * 4;
  float* xx_te = (float*)(w + off); off += NN * 4;
  float* xv = (float*)(w + off); off += NN * 4;
  float* rv = (float*)(w + off); off += NN * 4;
  float* p0 = (float*)(w + off); off += NN * 4;
  float* p1 = (float*)(w + off); off += NN * 4;
  float* qv = (float*)(w + off); off += NN * 4;
  off = (off + 255) & ~(size_t)255;
  double* rho = (double*)(w + off); off += (size_t)(NITER + 1) * 32 * 8;
  double* pqs = (double*)(w + off); off += (size_t)NITER * 32 * 8;
  double* pps = (double*)(w + off); off += (size_t)(NITER + 1) * 32 * 8;
  off = (off + 255) & ~(size_t)255;
  unsigned* bar = (unsigned*)(w + off); off += 2048;
  const int nslots = (3 * NITER + 2) * 32;
  if (ws_size < off) return;  // ~330KB; proven available since R3

  setup_zero<<<32, 256, 0, stream>>>(qv, out, rho, nslots, bar);
  row_norms<<<NN / 256, 256, 0, stream>>>(X_train, xx_tr);
  row_norms<<<NN / 256, 256, 0, stream>>>(X_test, xx_te);
  cg_init<<<NN / 256, 256, 0, stream>>>(y_train, xv, rv, p0, rho, pps);

  cg_persist<<<NBLK, 1024, 0, stream>>>(X_train, X_test, xx_tr, xx_te, xv, rv,
                                        p0, p1, qv, rho, pqs, pps, bar, out);
}

// Round 11
// 5888.605 us; speedup vs baseline: 1.7788x; 1.4353x over previous
//
#include <hip/hip_runtime.h>

// Kernel ridge regression, RBF kernel. N=M=8192, D=32, gamma=1/32, reg=1e-3.
// R11: persistent CG kernel with a FENCE-FREE global barrier. All cross-block
// data (p, r, q-partials, scalar slots, barrier words) moves through
// __hip_atomic_* RELAXED AGENT-scope ops (sc0/sc1: bypass L1/L2, coherent at
// L3) — so no acquire/release cache-maintenance (L2 inv/wb) is ever issued.
// R9/R10 counters showed MfmaUtil 6-8%, VALUBusy 9-12%: ~85% of time was the
// barrier's per-poll L2-invalidate storm, not compute.
// q accumulation: per-slice qpart stores (zero RMW contention; 1MB ws) with
// runtime fallback to atomicAdd if ws is small. beta LDS-broadcast by wave 0.
// Owner-private x/r/p carried in registers across all iterations.
// NITER=128 (R5: 80 iters failed at 0.070 — do not cut).

#define NN 8192
#define DD 32
#define REGL 1e-3f
#define NITER 128
#define NBLK 256
#define NC2 (-0.045084220027780106f)  // -gamma*log2e
#define SCF (0.3002806023f)           // sqrt(2*gamma*log2e)

typedef short v8s __attribute__((ext_vector_type(8)));
typedef float v4f __attribute__((ext_vector_type(4)));

__device__ __forceinline__ float fast_exp2(float x) {
#if __has_builtin(__builtin_amdgcn_exp2f)
  return __builtin_amdgcn_exp2f(x);
#else
  float r;
  asm("v_exp_f32 %0, %1" : "=v"(r) : "v"(x));
  return r;
#endif
}

// ---- relaxed agent-scope coherent accessors (bypass L1/L2, hit L3) ----
__device__ __forceinline__ float ld_f(const float* p) {
  return __hip_atomic_load(p, __ATOMIC_RELAXED, __HIP_MEMORY_SCOPE_AGENT);
}
__device__ __forceinline__ void st_f(float* p, float v) {
  __hip_atomic_store(p, v, __ATOMIC_RELAXED, __HIP_MEMORY_SCOPE_AGENT);
}
__device__ __forceinline__ double ld_d(const double* p) {
  return __hip_atomic_load(p, __ATOMIC_RELAXED, __HIP_MEMORY_SCOPE_AGENT);
}
__device__ __forceinline__ void add_d(double* p, double v) {
  __hip_atomic_fetch_add(p, v, __ATOMIC_RELAXED, __HIP_MEMORY_SCOPE_AGENT);
}

__device__ __forceinline__ ushort f2bf(float x) {  // RNE float->bf16 bits
  unsigned u = __float_as_uint(x);
  return (ushort)((u + 0x7fff + ((u >> 16) & 1)) >> 16);
}
__device__ __forceinline__ float bf2f(ushort b) {
  return __uint_as_float(((unsigned)b) << 16);
}

__device__ __forceinline__ double bfly64_d(double v) {
#pragma unroll
  for (int m = 1; m < 64; m <<= 1) v += __shfl_xor(v, m, 64);
  return v;
}
__device__ __forceinline__ double bfly32_d(double v) {
#pragma unroll
  for (int m = 1; m < 32; m <<= 1) v += __shfl_xor(v, m, 64);
  return v;
}
__device__ __forceinline__ double wave_down_sum_d(double v) {
#pragma unroll
  for (int off = 32; off > 0; off >>= 1) v += __shfl_down(v, off, 64);
  return v;
}

// ---- fence-free hierarchical global barrier ----
// bar: [0..255] 16 group counters stride 16; [256] root; [272] generation.
// All ops RELAXED agent-scope (coherent at L3, no cache maintenance).
// waitcnt(0) by every wave before s_barrier drains each wave's global
// stores/atomics; thread 0 then publishes arrival. Publisher waitcnts after
// counter resets so resets are applied at L3 before the generation bump.
__device__ __forceinline__ void gbarrier(unsigned* bar) {
  __builtin_amdgcn_s_waitcnt(0);  // per-wave drain of outstanding vmem
  __syncthreads();
  if (threadIdx.x == 0) {
    unsigned* gen = bar + 272;
    unsigned g =
        __hip_atomic_load(gen, __ATOMIC_RELAXED, __HIP_MEMORY_SCOPE_AGENT);
    unsigned a = __hip_atomic_fetch_add(&bar[(blockIdx.x >> 4) * 16], 1u,
                                        __ATOMIC_RELAXED,
                                        __HIP_MEMORY_SCOPE_AGENT);
    bool pub = false;
    if (a == 15u) {
      unsigned ra = __hip_atomic_fetch_add(bar + 256, 1u, __ATOMIC_RELAXED,
                                           __HIP_MEMORY_SCOPE_AGENT);
      if (ra == 15u) {
#pragma unroll
        for (int k = 0; k < 16; ++k)
          __hip_atomic_store(&bar[k * 16], 0u, __ATOMIC_RELAXED,
                             __HIP_MEMORY_SCOPE_AGENT);
        __hip_atomic_store(bar + 256, 0u, __ATOMIC_RELAXED,
                           __HIP_MEMORY_SCOPE_AGENT);
        __builtin_amdgcn_s_waitcnt(0);  // resets visible before publish
        __hip_atomic_store(gen, g + 1u, __ATOMIC_RELAXED,
                           __HIP_MEMORY_SCOPE_AGENT);
        pub = true;
      }
    }
    if (!pub) {
      unsigned t = 0;
      while (__hip_atomic_load(gen, __ATOMIC_RELAXED,
                               __HIP_MEMORY_SCOPE_AGENT) == g) {
        if (t < 64)
          __builtin_amdgcn_s_sleep(1);
        else
          __builtin_amdgcn_s_sleep(8);
        if (++t > (1u << 20)) break;  // escape hatch: fail, don't hang
      }
    }
  }
  __atomic_signal_fence(__ATOMIC_SEQ_CST);  // compiler reorder guard
  __syncthreads();
}

// hi/lo bf16 fragment from global X: lane holds row `row`, k = kb..kb+7.
__device__ __forceinline__ void conv_frag(const float* __restrict__ X, int row,
                                          int kb, v8s& h, v8s& l) {
  const float4* rp = (const float4*)(X + (size_t)row * DD + kb);
  float4 f0 = rp[0], f1 = rp[1];
  float f[8] = {f0.x, f0.y, f0.z, f0.w, f1.x, f1.y, f1.z, f1.w};
  union {
    v8s v;
    ushort u[8];
  } H, L;
#pragma unroll
  for (int j = 0; j < 8; ++j) {
    float fs = SCF * f[j];
    ushort hb = f2bf(fs);
    H.u[j] = hb;
    L.u[j] = f2bf(fs - bf2f(hb));
  }
  h = H.v;
  l = L.v;
}

// ---------------- setup kernels ----------------

__global__ void setup_zero(float* __restrict__ q, float* __restrict__ out,
                           double* __restrict__ slots, int nsl,
                           unsigned* __restrict__ bar) {
  int i = blockIdx.x * 256 + threadIdx.x;
  if (i < NN) {
    q[i] = 0.f;
    out[i] = 0.f;
  }
  int st = gridDim.x * 256;
  for (int k = i; k < nsl; k += st) slots[k] = 0.0;
  if (i < 512) bar[i] = 0u;
}

// stores NC2 * ||x||^2
__global__ void row_norms(const float* __restrict__ X, float* __restrict__ xx) {
  int i = blockIdx.x * blockDim.x + threadIdx.x;
  if (i < NN) {
    const float4* row = (const float4*)(X + (size_t)i * DD);
    float s = 0.f;
#pragma unroll
    for (int k = 0; k < DD / 4; ++k) {
      float4 v = row[k];
      s += v.x * v.x + v.y * v.y + v.z * v.z + v.w * v.w;
    }
    xx[i] = NC2 * s;
  }
}

__global__ __launch_bounds__(256) void cg_init(const float* __restrict__ y,
                                               float* __restrict__ r,
                                               float* __restrict__ p,
                                               double* __restrict__ rho0,
                                               double* __restrict__ pp0) {
  int i = blockIdx.x * 256 + threadIdx.x;
  float v = y[i];
  r[i] = v;
  p[i] = v;
  __shared__ double sred[4];
  double acc = wave_down_sum_d((double)v * (double)v);
  if ((threadIdx.x & 63) == 0) sred[threadIdx.x >> 6] = acc;
  __syncthreads();
  if (threadIdx.x == 0) {
    double t = sred[0] + sred[1] + sred[2] + sred[3];
    rho0[blockIdx.x] = t;
    pp0[blockIdx.x] = t;
  }
}

// ---------------- matvec compute core (4 row-tiles / wave) ----------------
__device__ __forceinline__ void mv_compute(const v8s* ah, const v8s* al,
                                           const ushort (*Bh)[512],
                                           const ushort (*Bl)[512],
                                           const float* Wj, int lane,
                                           float racc[4][4]) {
  const int n = lane & 15;
  for (int t = 0; t < 16; ++t) {
    v8s bh = *(const v8s*)&Bh[t][lane * 8];
    v8s bl = *(const v8s*)&Bl[t][lane * 8];
    float wn = Wj[t * 16 + n];
#pragma unroll
    for (int rs = 0; rs < 4; ++rs) {
      v4f c = {0.f, 0.f, 0.f, 0.f};
      c = __builtin_amdgcn_mfma_f32_16x16x32_bf16(al[rs], bh, c, 0, 0, 0);
      c = __builtin_amdgcn_mfma_f32_16x16x32_bf16(ah[rs], bl, c, 0, 0, 0);
      c = __builtin_amdgcn_mfma_f32_16x16x32_bf16(ah[rs], bh, c, 0, 0, 0);
#pragma unroll
      for (int u = 0; u < 4; ++u)
        racc[rs][u] = fmaf(fast_exp2(c[u]), wn, racc[rs][u]);
    }
  }
}

// ---------------- persistent CG kernel ----------------
// Grid 256 blocks x 1024 threads (16 waves): 8 rowblocks (1024 rows) x 32
// slices (256 cols). Each block owns vector elements [32b, 32b+32) — owner
// keeps x, r, p in REGISTERS (tid<32) and publishes p/r via atomic stores.

__global__ __launch_bounds__(1024, 4) void cg_persist(
    const float* __restrict__ Xtr, const float* __restrict__ Xte,
    const float* __restrict__ xx_tr, const float* __restrict__ xx_te,
    float* __restrict__ xv, float* __restrict__ rv, float* __restrict__ p0,
    float* __restrict__ p1, float* __restrict__ q, float* __restrict__ qpart,
    double* __restrict__ rho, double* __restrict__ pqs,
    double* __restrict__ pps, unsigned* __restrict__ bar,
    float* __restrict__ out, int useqp) {
  __shared__ __align__(16) ushort Bh[16][512];  // 16 col-tiles, hi plane
  __shared__ __align__(16) ushort Bl[16][512];  // lo plane
  __shared__ float Wj[256];
  __shared__ double sredq[16];
  __shared__ float s_beta;

  const int tid = threadIdx.x;
  const int lane = tid & 63;
  const int wid = tid >> 6;  // 0..15
  const int n = lane & 15, q4 = lane >> 4;
  const int rbi = blockIdx.x & 7;        // rowblock: 1024 rows
  const int sli = blockIdx.x >> 3;       // slice: 256 cols
  const int i0 = rbi * 1024 + wid * 64;  // 64 rows per wave
  const int jbase = sli * 256;
  const int iown = blockIdx.x * 32 + (tid & 31);  // owned element (tid<32)

  // ---- stage B-slice into LDS once (frag layout, scaled, hi/lo) ----
  {
    int c = tid & 255;
    int j = jbase + c;
    int g = tid >> 8;  // 0..3
    int tile = c >> 4, cl = c & 15;
    const float4* rp = (const float4*)(Xtr + (size_t)j * DD);
    float4 f0 = rp[2 * g], f1 = rp[2 * g + 1];
    float f[8] = {f0.x, f0.y, f0.z, f0.w, f1.x, f1.y, f1.z, f1.w};
    union {
      ushort u[8];
      uint4 qq;
    } H, L;
#pragma unroll
    for (int e = 0; e < 8; ++e) {
      float fs = SCF * f[e];
      ushort hb = f2bf(fs);
      H.u[e] = hb;
      L.u[e] = f2bf(fs - bf2f(hb));
    }
    int ln = cl + 16 * g;
    *(uint4*)&Bh[tile][ln * 8] = H.qq;
    *(uint4*)&Bl[tile][ln * 8] = L.qq;
  }

  // ---- A fragments (64 rows per wave) in registers, converted once ----
  v8s ah[4], al[4];
#pragma unroll
  for (int rs = 0; rs < 4; ++rs)
    conv_frag(Xtr, i0 + rs * 16 + n, q4 * 8, ah[rs], al[rs]);

  // ---- owner-private state in registers ----
  float xreg = 0.f, rreg = 0.f, preg = 0.f;
  if (tid < 32) {
    preg = ld_f(p0 + iown);  // = y (cg_init)
    rreg = preg;
  }
  double rho_k = 0.0, rho_prev = 0.0;
  __syncthreads();

  for (int it = 0; it < NITER; ++it) {
    float* pcur = (it & 1) ? p1 : p0;
    float* poth = (it & 1) ? p0 : p1;
    const int first = (it == 0);

    // wave 0: rho_k from slots; beta; broadcast via LDS
    if (wid == 0) {
      double v = ld_d(rho + (size_t)it * 32 + (lane & 31));
      rho_k = bfly32_d(v);
      float b = first ? 0.f : (float)(rho_k / rho_prev);
      rho_prev = rho_k;
      if (lane == 0) s_beta = b;
    }
    __syncthreads();
    const float beta = s_beta;

    // owners: advance p in registers, publish; p.p partial
    if (tid < 32 && !first) {
      preg = fmaf(beta, preg, rreg);
      st_f(pcur + iown, preg);
      double c = bfly32_d((double)preg * (double)preg);
      if (tid == 0) add_d(&pps[(size_t)it * 32 + (blockIdx.x & 31)], c);
    }
    // stage weights: Wj' = p_j * 2^{NC2*||xb_j||^2}
    if (tid < 256) {
      int j = jbase + tid;
      float pj = first ? ld_f(pcur + j)
                       : fmaf(beta, ld_f(poth + j), ld_f(rv + j));
      Wj[tid] = pj * fast_exp2(xx_tr[j]);
    }
    __syncthreads();

    float racc[4][4] = {};
    mv_compute(ah, al, Bh, Bl, Wj, lane, racc);

    // reduce each row over the 16 col-lanes (C/D layout: col = lane&15)
#pragma unroll
    for (int rs = 0; rs < 4; ++rs)
#pragma unroll
      for (int u = 0; u < 4; ++u) {
#pragma unroll
        for (int m = 1; m < 16; m <<= 1)
          racc[rs][u] += __shfl_xor(racc[rs][u], m, 64);
      }
    double cpq = 0.0;
    if (n == 0) {
#pragma unroll
      for (int rs = 0; rs < 4; ++rs)
#pragma unroll
        for (int u = 0; u < 4; ++u) {
          int row = i0 + rs * 16 + q4 * 4 + u;
          float qc = racc[rs][u] * fast_exp2(xx_tr[row]);  // 2^{nxA}
          if (useqp)
            st_f(&qpart[(size_t)sli * NN + row], qc);  // contention-free
          else
            atomicAdd(&q[row], qc);
          float pnr = first ? ld_f(pcur + row)
                            : fmaf(beta, ld_f(poth + row), ld_f(rv + row));
          cpq += (double)qc * (double)pnr;
        }
    }
    // block-level p.Kp reduction -> single slot add per block
    cpq = bfly64_d(cpq);
    if (lane == 0) sredq[wid] = cpq;
    __syncthreads();
    if (tid == 0) {
      double t = 0.0;
#pragma unroll
      for (int k3 = 0; k3 < 16; ++k3) t += sredq[k3];
      add_d(&pqs[(size_t)it * 32 + (blockIdx.x & 31)], t);
    }
    gbarrier(bar);  // q, pq, pp complete

    // ---- phase B (distributed): owners update x, r in registers ----
    if (tid < 32) {
      double pqv = bfly32_d(ld_d(pqs + (size_t)it * 32 + tid));
      double ppv = bfly32_d(ld_d(pps + (size_t)it * 32 + tid));
      float alpha = (float)(rho_k / (pqv + (double)REGL * ppv));
      float qtot;
      if (useqp) {
        float s = 0.f;
#pragma unroll
        for (int s2 = 0; s2 < 32; ++s2)
          s += ld_f(&qpart[(size_t)s2 * NN + iown]);
        qtot = s;
      } else {
        qtot = ld_f(q + iown);
      }
      xreg = fmaf(alpha, preg, xreg);
      rreg = rreg - alpha * (qtot + REGL * preg);
      st_f(rv + iown, rreg);
      if (!useqp) st_f(q + iown, 0.f);
      if (it == NITER - 1) st_f(xv + iown, xreg);
      double c = bfly32_d((double)rreg * (double)rreg);
      if (tid == 0) add_d(&rho[(size_t)(it + 1) * 32 + (blockIdx.x & 31)], c);
    }
    gbarrier(bar);  // r, rho, x, q-zero complete
  }

  // ---- predict: out = K_test @ alpha, same B-slice in LDS ----
  {
    v8s th[4], tl[4];
#pragma unroll
    for (int rs = 0; rs < 4; ++rs)
      conv_frag(Xte, i0 + rs * 16 + n, q4 * 8, th[rs], tl[rs]);
    if (tid < 256) {
      int j = jbase + tid;
      Wj[tid] = ld_f(xv + j) * fast_exp2(xx_tr[j]);
    }
    __syncthreads();
    float racc[4][4] = {};
    mv_compute(th, tl, Bh, Bl, Wj, lane, racc);
#pragma unroll
    for (int rs = 0; rs < 4; ++rs)
#pragma unroll
      for (int u = 0; u < 4; ++u) {
#pragma unroll
        for (int m = 1; m < 16; m <<= 1)
          racc[rs][u] += __shfl_xor(racc[rs][u], m, 64);
      }
    if (n == 0) {
#pragma unroll
      for (int rs = 0; rs < 4; ++rs)
#pragma unroll
        for (int u = 0; u < 4; ++u) {
          int row = i0 + rs * 16 + q4 * 4 + u;
          float oc = racc[rs][u] * fast_exp2(xx_te[row]);
          if (useqp)
            st_f(&qpart[(size_t)sli * NN + row], oc);
          else
            atomicAdd(&q[row], oc);
        }
    }
    gbarrier(bar);
    if (tid < 32) {
      float s = 0.f;
      if (useqp) {
#pragma unroll
        for (int s2 = 0; s2 < 32; ++s2)
          s += ld_f(&qpart[(size_t)s2 * NN + iown]);
      } else {
        s = ld_f(q + iown);
      }
      out[iown] = s;  // kernel-end writeback makes this visible to the host
    }
  }
}

// ---------------- launcher ----------------

extern "C" void kernel_launch(void* const* d_in, const int* in_sizes, int n_in,
                              void* d_out, int out_size, void* d_ws,
                              size_t ws_size, hipStream_t stream) {
  const float* X_train = (const float*)d_in[0];
  const float* y_train = (const float*)d_in[1];
  const float* X_test = (const float*)d_in[2];
  float* out = (float*)d_out;

  char* w = (char*)d_ws;
  size_t off = 0;
  float* xx_tr = (float*)(w + off); off += NN * 4;
  float* xx_te = (float*)(w + off); off += NN * 4;
  float* xv = (float*)(w + off); off += NN * 4;
  float* rv = (float*)(w + off); off += NN * 4;
  float* p0 = (float*)(w + off); off += NN * 4;
  float* p1 = (float*)(w + off); off += NN * 4;
  float* qv = (float*)(w + off); off += NN * 4;
  off = (off + 255) & ~(size_t)255;
  double* rho = (double*)(w + off); off += (size_t)(NITER + 1) * 32 * 8;
  double* pqs = (double*)(w + off); off += (size_t)NITER * 32 * 8;
  double* pps = (double*)(w + off); off += (size_t)(NITER + 1) * 32 * 8;
  off = (off + 255) & ~(size_t)255;
  unsigned* bar = (unsigned*)(w + off); off += 2048;
  const int nslots = (3 * NITER + 2) * 32;
  if (ws_size < off) return;  // ~330KB; proven available since R3

  // qpart: 32 slices x NN fp32 = 1MB, used if workspace allows
  off = (off + 255) & ~(size_t)255;
  int useqp = (ws_size >= off + (size_t)32 * NN * 4) ? 1 : 0;
  float* qpart = useqp ? (float*)(w + off) : qv;

  setup_zero<<<32, 256, 0, stream>>>(qv, out, rho, nslots, bar);
  row_norms<<<NN / 256, 256, 0, stream>>>(X_train, xx_tr);
  row_norms<<<NN / 256, 256, 0, stream>>>(X_test, xx_te);
  cg_init<<<NN / 256, 256, 0, stream>>>(y_train, rv, p0, rho, pps);

  cg_persist<<<NBLK, 1024, 0, stream>>>(X_train, X_test, xx_tr, xx_te, xv, rv,
                                        p0, p1, qv, qpart, rho, pqs, pps, bar,
                                        out, useqp);
}

// Round 12
// 3471.325 us; speedup vs baseline: 3.0175x; 1.6964x over previous
//
#include <hip/hip_runtime.h>

// Kernel ridge regression, RBF kernel. N=M=8192, D=32, gamma=1/32, reg=1e-3.
// R12: R11's fence-free persistent CG, with every serialized agent-scope
// scalar-load chain parallelized across the block's 1024 threads:
//  - phase B q-reduction: 1 load/thread + LDS transpose (was 32 dependent
//    ~900cy L3 round-trips on 32 owner threads ≈ 12us/iter),
//  - epilogue p_rows: staged to LDS by all threads pre-compute (was 32
//    serialized ld_f on the sparse n==0 lanes ≈ 12us/iter),
//  - exp norm factors cached in LDS (Erow/Ebj), computed once.
// R11 counters: MfmaUtil 11.5%, VALUBusy 17.7% at 46us/iter — ~70% stall on
// exactly these chains. Barrier/algebra unchanged (validated R11).
// NITER=128 (R5: 80 iters failed at 0.070 — do not cut).

#define NN 8192
#define DD 32
#define REGL 1e-3f
#define NITER 128
#define NBLK 256
#define NC2 (-0.045084220027780106f)  // -gamma*log2e
#define SCF (0.3002806023f)           // sqrt(2*gamma*log2e)

typedef short v8s __attribute__((ext_vector_type(8)));
typedef float v4f __attribute__((ext_vector_type(4)));

__device__ __forceinline__ float fast_exp2(float x) {
#if __has_builtin(__builtin_amdgcn_exp2f)
  return __builtin_amdgcn_exp2f(x);
#else
  float r;
  asm("v_exp_f32 %0, %1" : "=v"(r) : "v"(x));
  return r;
#endif
}

// ---- relaxed agent-scope coherent accessors ----
__device__ __forceinline__ float ld_f(const float* p) {
  return __hip_atomic_load(p, __ATOMIC_RELAXED, __HIP_MEMORY_SCOPE_AGENT);
}
__device__ __forceinline__ void st_f(float* p, float v) {
  __hip_atomic_store(p, v, __ATOMIC_RELAXED, __HIP_MEMORY_SCOPE_AGENT);
}
__device__ __forceinline__ double ld_d(const double* p) {
  return __hip_atomic_load(p, __ATOMIC_RELAXED, __HIP_MEMORY_SCOPE_AGENT);
}
__device__ __forceinline__ void add_d(double* p, double v) {
  __hip_atomic_fetch_add(p, v, __ATOMIC_RELAXED, __HIP_MEMORY_SCOPE_AGENT);
}

__device__ __forceinline__ ushort f2bf(float x) {  // RNE float->bf16 bits
  unsigned u = __float_as_uint(x);
  return (ushort)((u + 0x7fff + ((u >> 16) & 1)) >> 16);
}
__device__ __forceinline__ float bf2f(ushort b) {
  return __uint_as_float(((unsigned)b) << 16);
}

__device__ __forceinline__ double bfly64_d(double v) {
#pragma unroll
  for (int m = 1; m < 64; m <<= 1) v += __shfl_xor(v, m, 64);
  return v;
}
__device__ __forceinline__ double bfly32_d(double v) {
#pragma unroll
  for (int m = 1; m < 32; m <<= 1) v += __shfl_xor(v, m, 64);
  return v;
}
__device__ __forceinline__ double wave_down_sum_d(double v) {
#pragma unroll
  for (int off = 32; off > 0; off >>= 1) v += __shfl_down(v, off, 64);
  return v;
}

// ---- fence-free hierarchical global barrier (validated R11) ----
__device__ __forceinline__ void gbarrier(unsigned* bar) {
  __builtin_amdgcn_s_waitcnt(0);
  __syncthreads();
  if (threadIdx.x == 0) {
    unsigned* gen = bar + 272;
    unsigned g =
        __hip_atomic_load(gen, __ATOMIC_RELAXED, __HIP_MEMORY_SCOPE_AGENT);
    unsigned a = __hip_atomic_fetch_add(&bar[(blockIdx.x >> 4) * 16], 1u,
                                        __ATOMIC_RELAXED,
                                        __HIP_MEMORY_SCOPE_AGENT);
    bool pub = false;
    if (a == 15u) {
      unsigned ra = __hip_atomic_fetch_add(bar + 256, 1u, __ATOMIC_RELAXED,
                                           __HIP_MEMORY_SCOPE_AGENT);
      if (ra == 15u) {
#pragma unroll
        for (int k = 0; k < 16; ++k)
          __hip_atomic_store(&bar[k * 16], 0u, __ATOMIC_RELAXED,
                             __HIP_MEMORY_SCOPE_AGENT);
        __hip_atomic_store(bar + 256, 0u, __ATOMIC_RELAXED,
                           __HIP_MEMORY_SCOPE_AGENT);
        __builtin_amdgcn_s_waitcnt(0);
        __hip_atomic_store(gen, g + 1u, __ATOMIC_RELAXED,
                           __HIP_MEMORY_SCOPE_AGENT);
        pub = true;
      }
    }
    if (!pub) {
      unsigned t = 0;
      while (__hip_atomic_load(gen, __ATOMIC_RELAXED,
                               __HIP_MEMORY_SCOPE_AGENT) == g) {
        if (t < 64)
          __builtin_amdgcn_s_sleep(1);
        else
          __builtin_amdgcn_s_sleep(8);
        if (++t > (1u << 20)) break;  // escape hatch: fail, don't hang
      }
    }
  }
  __atomic_signal_fence(__ATOMIC_SEQ_CST);
  __syncthreads();
}

// hi/lo bf16 fragment from global X: lane holds row `row`, k = kb..kb+7.
__device__ __forceinline__ void conv_frag(const float* __restrict__ X, int row,
                                          int kb, v8s& h, v8s& l) {
  const float4* rp = (const float4*)(X + (size_t)row * DD + kb);
  float4 f0 = rp[0], f1 = rp[1];
  float f[8] = {f0.x, f0.y, f0.z, f0.w, f1.x, f1.y, f1.z, f1.w};
  union {
    v8s v;
    ushort u[8];
  } H, L;
#pragma unroll
  for (int j = 0; j < 8; ++j) {
    float fs = SCF * f[j];
    ushort hb = f2bf(fs);
    H.u[j] = hb;
    L.u[j] = f2bf(fs - bf2f(hb));
  }
  h = H.v;
  l = L.v;
}

// ---------------- setup kernels ----------------

__global__ void setup_zero(float* __restrict__ q, float* __restrict__ out,
                           double* __restrict__ slots, int nsl,
                           unsigned* __restrict__ bar) {
  int i = blockIdx.x * 256 + threadIdx.x;
  if (i < NN) {
    q[i] = 0.f;
    out[i] = 0.f;
  }
  int st = gridDim.x * 256;
  for (int k = i; k < nsl; k += st) slots[k] = 0.0;
  if (i < 512) bar[i] = 0u;
}

// stores NC2 * ||x||^2
__global__ void row_norms(const float* __restrict__ X, float* __restrict__ xx) {
  int i = blockIdx.x * blockDim.x + threadIdx.x;
  if (i < NN) {
    const float4* row = (const float4*)(X + (size_t)i * DD);
    float s = 0.f;
#pragma unroll
    for (int k = 0; k < DD / 4; ++k) {
      float4 v = row[k];
      s += v.x * v.x + v.y * v.y + v.z * v.z + v.w * v.w;
    }
    xx[i] = NC2 * s;
  }
}

__global__ __launch_bounds__(256) void cg_init(const float* __restrict__ y,
                                               float* __restrict__ r,
                                               float* __restrict__ p,
                                               double* __restrict__ rho0,
                                               double* __restrict__ pp0) {
  int i = blockIdx.x * 256 + threadIdx.x;
  float v = y[i];
  r[i] = v;
  p[i] = v;
  __shared__ double sred[4];
  double acc = wave_down_sum_d((double)v * (double)v);
  if ((threadIdx.x & 63) == 0) sred[threadIdx.x >> 6] = acc;
  __syncthreads();
  if (threadIdx.x == 0) {
    double t = sred[0] + sred[1] + sred[2] + sred[3];
    rho0[blockIdx.x] = t;
    pp0[blockIdx.x] = t;
  }
}

// ---------------- matvec compute core (4 row-tiles / wave) ----------------
__device__ __forceinline__ void mv_compute(const v8s* ah, const v8s* al,
                                           const ushort (*Bh)[512],
                                           const ushort (*Bl)[512],
                                           const float* Wj, int lane,
                                           float racc[4][4]) {
  const int n = lane & 15;
  for (int t = 0; t < 16; ++t) {
    v8s bh = *(const v8s*)&Bh[t][lane * 8];
    v8s bl = *(const v8s*)&Bl[t][lane * 8];
    float wn = Wj[t * 16 + n];
#pragma unroll
    for (int rs = 0; rs < 4; ++rs) {
      v4f c = {0.f, 0.f, 0.f, 0.f};
      c = __builtin_amdgcn_mfma_f32_16x16x32_bf16(al[rs], bh, c, 0, 0, 0);
      c = __builtin_amdgcn_mfma_f32_16x16x32_bf16(ah[rs], bl, c, 0, 0, 0);
      c = __builtin_amdgcn_mfma_f32_16x16x32_bf16(ah[rs], bh, c, 0, 0, 0);
#pragma unroll
      for (int u = 0; u < 4; ++u)
        racc[rs][u] = fmaf(fast_exp2(c[u]), wn, racc[rs][u]);
    }
  }
}

// ---------------- persistent CG kernel ----------------
// Grid 256 blocks x 1024 threads (16 waves): 8 rowblocks (1024 rows) x 32
// slices (256 cols). Block owns vector elements [32b, 32b+32) in registers.

__global__ __launch_bounds__(1024, 4) void cg_persist(
    const float* __restrict__ Xtr, const float* __restrict__ Xte,
    const float* __restrict__ xx_tr, const float* __restrict__ xx_te,
    float* __restrict__ xv, float* __restrict__ rv, float* __restrict__ p0,
    float* __restrict__ p1, float* __restrict__ q, float* __restrict__ qpart,
    double* __restrict__ rho, double* __restrict__ pqs,
    double* __restrict__ pps, unsigned* __restrict__ bar,
    float* __restrict__ out, int useqp) {
  __shared__ __align__(16) ushort Bh[16][512];  // 16 col-tiles, hi plane
  __shared__ __align__(16) ushort Bl[16][512];  // lo plane
  __shared__ float Wj[256];
  __shared__ float Ebj[256];    // 2^{NC2*||xb_j||^2} for block's cols
  __shared__ float Erow[1024];  // 2^{NC2*||xa_i||^2} for block's rows
  __shared__ float Prow[1024];  // p_k staged for block's rows
  __shared__ float qred[32][33];
  __shared__ double sredq[16];
  __shared__ float s_beta;

  const int tid = threadIdx.x;
  const int lane = tid & 63;
  const int wid = tid >> 6;  // 0..15
  const int n = lane & 15, q4 = lane >> 4;
  const int rbi = blockIdx.x & 7;        // rowblock: 1024 rows
  const int sli = blockIdx.x >> 3;       // slice: 256 cols
  const int i0 = rbi * 1024 + wid * 64;  // 64 rows per wave
  const int jbase = sli * 256;
  const int iown = blockIdx.x * 32 + (tid & 31);  // owned element (tid<32)

  // ---- stage B-slice into LDS once (frag layout, scaled, hi/lo) ----
  {
    int c = tid & 255;
    int j = jbase + c;
    int g = tid >> 8;  // 0..3
    int tile = c >> 4, cl = c & 15;
    const float4* rp = (const float4*)(Xtr + (size_t)j * DD);
    float4 f0 = rp[2 * g], f1 = rp[2 * g + 1];
    float f[8] = {f0.x, f0.y, f0.z, f0.w, f1.x, f1.y, f1.z, f1.w};
    union {
      ushort u[8];
      uint4 qq;
    } H, L;
#pragma unroll
    for (int e = 0; e < 8; ++e) {
      float fs = SCF * f[e];
      ushort hb = f2bf(fs);
      H.u[e] = hb;
      L.u[e] = f2bf(fs - bf2f(hb));
    }
    int ln = cl + 16 * g;
    *(uint4*)&Bh[tile][ln * 8] = H.qq;
    *(uint4*)&Bl[tile][ln * 8] = L.qq;
  }
  // ---- constant exp factors, cached once ----
  if (tid < 256) Ebj[tid] = fast_exp2(xx_tr[jbase + tid]);
  Erow[tid] = fast_exp2(xx_tr[rbi * 1024 + tid]);

  // ---- A fragments (64 rows per wave) in registers, converted once ----
  v8s ah[4], al[4];
#pragma unroll
  for (int rs = 0; rs < 4; ++rs)
    conv_frag(Xtr, i0 + rs * 16 + n, q4 * 8, ah[rs], al[rs]);

  // ---- owner-private state in registers ----
  float xreg = 0.f, rreg = 0.f, preg = 0.f;
  if (tid < 32) {
    preg = ld_f(p0 + iown);  // = y (cg_init)
    rreg = preg;
  }
  double rho_k = 0.0, rho_prev = 0.0;
  __syncthreads();

  for (int it = 0; it < NITER; ++it) {
    float* pcur = (it & 1) ? p1 : p0;
    float* poth = (it & 1) ? p0 : p1;
    const int first = (it == 0);

    // 1. beta (wave 0), broadcast via LDS
    if (wid == 0) {
      double v = ld_d(rho + (size_t)it * 32 + (lane & 31));
      rho_k = bfly32_d(v);
      float b = first ? 0.f : (float)(rho_k / rho_prev);
      rho_prev = rho_k;
      if (lane == 0) s_beta = b;
    }
    __syncthreads();
    const float beta = s_beta;

    // 2. owners: advance p in registers, publish; p.p partial
    if (tid < 32 && !first) {
      preg = fmaf(beta, preg, rreg);
      st_f(pcur + iown, preg);
      double c = bfly32_d((double)preg * (double)preg);
      if (tid == 0) add_d(&pps[(size_t)it * 32 + (blockIdx.x & 31)], c);
    }
    // 3a. Wj stage (256 threads, 2 parallel loads each)
    if (tid < 256) {
      int j = jbase + tid;
      float pj =
          first ? ld_f(pcur + j) : fmaf(beta, ld_f(poth + j), ld_f(rv + j));
      Wj[tid] = pj * Ebj[tid];
    }
    // 3b. Prow stage (all 1024 threads, 2 parallel loads each)
    {
      int row = rbi * 1024 + tid;
      float pr = first ? ld_f(pcur + row)
                       : fmaf(beta, ld_f(poth + row), ld_f(rv + row));
      Prow[tid] = pr;
    }
    __syncthreads();

    // 4. matvec
    float racc[4][4] = {};
    mv_compute(ah, al, Bh, Bl, Wj, lane, racc);
#pragma unroll
    for (int rs = 0; rs < 4; ++rs)
#pragma unroll
      for (int u = 0; u < 4; ++u) {
#pragma unroll
        for (int m = 1; m < 16; m <<= 1)
          racc[rs][u] += __shfl_xor(racc[rs][u], m, 64);
      }
    double cpq = 0.0;
    if (n == 0) {
#pragma unroll
      for (int rs = 0; rs < 4; ++rs)
#pragma unroll
        for (int u = 0; u < 4; ++u) {
          int lrow = wid * 64 + rs * 16 + q4 * 4 + u;
          int row = rbi * 1024 + lrow;
          float qc = racc[rs][u] * Erow[lrow];
          if (useqp)
            st_f(&qpart[(size_t)sli * NN + row], qc);
          else
            atomicAdd(&q[row], qc);
          cpq += (double)qc * (double)Prow[lrow];
        }
    }
    cpq = bfly64_d(cpq);
    if (lane == 0) sredq[wid] = cpq;
    __syncthreads();
    if (tid == 0) {
      double t = 0.0;
#pragma unroll
      for (int k3 = 0; k3 < 16; ++k3) t += sredq[k3];
      add_d(&pqs[(size_t)it * 32 + (blockIdx.x & 31)], t);
    }
    gbarrier(bar);  // q, pq, pp complete

    // 6. phase B: parallel q gather (1 load/thread), owners update
    if (useqp) {
      int s2 = tid >> 5, e = tid & 31;
      qred[e][s2] = ld_f(&qpart[(size_t)s2 * NN + blockIdx.x * 32 + e]);
    }
    __syncthreads();
    if (tid < 32) {
      double pqv = bfly32_d(ld_d(pqs + (size_t)it * 32 + tid));
      double ppv = bfly32_d(ld_d(pps + (size_t)it * 32 + tid));
      float alpha = (float)(rho_k / (pqv + (double)REGL * ppv));
      float qtot;
      if (useqp) {
        float s = 0.f;
#pragma unroll
        for (int s2 = 0; s2 < 32; ++s2) s += qred[tid][s2];
        qtot = s;
      } else {
        qtot = ld_f(q + iown);
      }
      xreg = fmaf(alpha, preg, xreg);
      rreg = rreg - alpha * (qtot + REGL * preg);
      st_f(rv + iown, rreg);
      if (!useqp) st_f(q + iown, 0.f);
      if (it == NITER - 1) st_f(xv + iown, xreg);
      double c = bfly32_d((double)rreg * (double)rreg);
      if (tid == 0) add_d(&rho[(size_t)(it + 1) * 32 + (blockIdx.x & 31)], c);
    }
    gbarrier(bar);  // r, rho, x, q-zero complete
  }

  // ---- predict: out = K_test @ alpha, same B-slice in LDS ----
  {
    v8s th[4], tl[4];
#pragma unroll
    for (int rs = 0; rs < 4; ++rs)
      conv_frag(Xte, i0 + rs * 16 + n, q4 * 8, th[rs], tl[rs]);
    if (tid < 256) Wj[tid] = ld_f(xv + jbase + tid) * Ebj[tid];
    Erow[tid] = fast_exp2(xx_te[rbi * 1024 + tid]);  // test-row factors
    __syncthreads();
    float racc[4][4] = {};
    mv_compute(th, tl, Bh, Bl, Wj, lane, racc);
#pragma unroll
    for (int rs = 0; rs < 4; ++rs)
#pragma unroll
      for (int u = 0; u < 4; ++u) {
#pragma unroll
        for (int m = 1; m < 16; m <<= 1)
          racc[rs][u] += __shfl_xor(racc[rs][u], m, 64);
      }
    if (n == 0) {
#pragma unroll
      for (int rs = 0; rs < 4; ++rs)
#pragma unroll
        for (int u = 0; u < 4; ++u) {
          int lrow = wid * 64 + rs * 16 + q4 * 4 + u;
          int row = rbi * 1024 + lrow;
          float oc = racc[rs][u] * Erow[lrow];
          if (useqp)
            st_f(&qpart[(size_t)sli * NN + row], oc);
          else
            atomicAdd(&q[row], oc);
        }
    }
    gbarrier(bar);
    if (useqp) {
      int s2 = tid >> 5, e = tid & 31;
      qred[e][s2] = ld_f(&qpart[(size_t)s2 * NN + blockIdx.x * 32 + e]);
    }
    __syncthreads();
    if (tid < 32) {
      float s = 0.f;
      if (useqp) {
#pragma unroll
        for (int s2 = 0; s2 < 32; ++s2) s += qred[tid][s2];
      } else {
        s = ld_f(q + iown);
      }
      out[iown] = s;  // kernel-end writeback
    }
  }
}

// ---------------- launcher ----------------

extern "C" void kernel_launch(void* const* d_in, const int* in_sizes, int n_in,
                              void* d_out, int out_size, void* d_ws,
                              size_t ws_size, hipStream_t stream) {
  const float* X_train = (const float*)d_in[0];
  const float* y_train = (const float*)d_in[1];
  const float* X_test = (const float*)d_in[2];
  float* out = (float*)d_out;

  char* w = (char*)d_ws;
  size_t off = 0;
  float* xx_tr = (float*)(w + off); off += NN * 4;
  float* xx_te = (float*)(w + off); off += NN * 4;
  float* xv = (float*)(w + off); off += NN * 4;
  float* rv = (float*)(w + off); off += NN * 4;
  float* p0 = (float*)(w + off); off += NN * 4;
  float* p1 = (float*)(w + off); off += NN * 4;
  float* qv = (float*)(w + off); off += NN * 4;
  off = (off + 255) & ~(size_t)255;
  double* rho = (double*)(w + off); off += (size_t)(NITER + 1) * 32 * 8;
  double* pqs = (double*)(w + off); off += (size_t)NITER * 32 * 8;
  double* pps = (double*)(w + off); off += (size_t)(NITER + 1) * 32 * 8;
  off = (off + 255) & ~(size_t)255;
  unsigned* bar = (unsigned*)(w + off); off += 2048;
  const int nslots = (3 * NITER + 2) * 32;
  if (ws_size < off) return;  // ~330KB; proven available since R3

  // qpart: 32 slices x NN fp32 = 1MB, used if workspace allows
  off = (off + 255) & ~(size_t)255;
  int useqp = (ws_size >= off + (size_t)32 * NN * 4) ? 1 : 0;
  float* qpart = useqp ? (float*)(w + off) : qv;

  setup_zero<<<32, 256, 0, stream>>>(qv, out, rho, nslots, bar);
  row_norms<<<NN / 256, 256, 0, stream>>>(X_train, xx_tr);
  row_norms<<<NN / 256, 256, 0, stream>>>(X_test, xx_te);
  cg_init<<<NN / 256, 256, 0, stream>>>(y_train, rv, p0, rho, pps);

  cg_persist<<<NBLK, 1024, 0, stream>>>(X_train, X_test, xx_tr, xx_te, xv, rv,
                                        p0, p1, qv, qpart, rho, pqs, pps, bar,
                                        out, useqp);
}

// Round 13
// 2710.843 us; speedup vs baseline: 3.8641x; 1.2805x over previous
//
#include <hip/hip_runtime.h>

// Kernel ridge regression, RBF kernel. N=M=8192, D=32, gamma=1/32, reg=1e-3.
// R13: Chronopoulos-Gear (single-reduction) CG in a persistent kernel —
// ONE global barrier per iteration (R12 had two; barrier ~3us each).
// Matvec input is r_k; rho=r.r and mu=r.Kr are computed PRE-barrier
// (rho from LDS Rrow by slice-0 blocks, mu via the cpq pattern); after the
// barrier every block derives alpha/beta from slots via the CG-CG recurrence
// and updates purely BLOCK-LOCAL LDS state: Rrow/Qrow (its 1024 rows),
// Rcol/Qcol/Pcol/Xcol (its 256 cols), with w gathered from qpart in flat
// ascending slice order (replicas stay bitwise identical). No global p/r/x
// vectors in the loop. qpart double-buffered (2MB) so iter k+1's writes
// can't race iter k's gathers; single-buffer + 2nd barrier fallback.
// Fence-free relaxed agent-scope atomics throughout (validated R11/R12).
// NITER=128 (R5: 80 iters failed at 0.070 — do not cut).

#define NN 8192
#define DD 32
#define REGL 1e-3f
#define NITER 128
#define NBLK 256
#define NC2 (-0.045084220027780106f)  // -gamma*log2e
#define SCF (0.3002806023f)           // sqrt(2*gamma*log2e)

typedef short v8s __attribute__((ext_vector_type(8)));
typedef float v4f __attribute__((ext_vector_type(4)));

__device__ __forceinline__ float fast_exp2(float x) {
#if __has_builtin(__builtin_amdgcn_exp2f)
  return __builtin_amdgcn_exp2f(x);
#else
  float r;
  asm("v_exp_f32 %0, %1" : "=v"(r) : "v"(x));
  return r;
#endif
}

// ---- relaxed agent-scope coherent accessors ----
__device__ __forceinline__ float ld_f(const float* p) {
  return __hip_atomic_load(p, __ATOMIC_RELAXED, __HIP_MEMORY_SCOPE_AGENT);
}
__device__ __forceinline__ void st_f(float* p, float v) {
  __hip_atomic_store(p, v, __ATOMIC_RELAXED, __HIP_MEMORY_SCOPE_AGENT);
}
__device__ __forceinline__ double ld_d(const double* p) {
  return __hip_atomic_load(p, __ATOMIC_RELAXED, __HIP_MEMORY_SCOPE_AGENT);
}
__device__ __forceinline__ void add_d(double* p, double v) {
  __hip_atomic_fetch_add(p, v, __ATOMIC_RELAXED, __HIP_MEMORY_SCOPE_AGENT);
}

__device__ __forceinline__ ushort f2bf(float x) {  // RNE float->bf16 bits
  unsigned u = __float_as_uint(x);
  return (ushort)((u + 0x7fff + ((u >> 16) & 1)) >> 16);
}
__device__ __forceinline__ float bf2f(ushort b) {
  return __uint_as_float(((unsigned)b) << 16);
}

__device__ __forceinline__ double bfly64_d(double v) {
#pragma unroll
  for (int m = 1; m < 64; m <<= 1) v += __shfl_xor(v, m, 64);
  return v;
}
__device__ __forceinline__ double bfly32_d(double v) {
#pragma unroll
  for (int m = 1; m < 32; m <<= 1) v += __shfl_xor(v, m, 64);
  return v;
}
__device__ __forceinline__ double wave_down_sum_d(double v) {
#pragma unroll
  for (int off = 32; off > 0; off >>= 1) v += __shfl_down(v, off, 64);
  return v;
}

// ---- fence-free hierarchical global barrier (validated R11/R12) ----
__device__ __forceinline__ void gbarrier(unsigned* bar) {
  __builtin_amdgcn_s_waitcnt(0);
  __syncthreads();
  if (threadIdx.x == 0) {
    unsigned* gen = bar + 272;
    unsigned g =
        __hip_atomic_load(gen, __ATOMIC_RELAXED, __HIP_MEMORY_SCOPE_AGENT);
    unsigned a = __hip_atomic_fetch_add(&bar[(blockIdx.x >> 4) * 16], 1u,
                                        __ATOMIC_RELAXED,
                                        __HIP_MEMORY_SCOPE_AGENT);
    bool pub = false;
    if (a == 15u) {
      unsigned ra = __hip_atomic_fetch_add(bar + 256, 1u, __ATOMIC_RELAXED,
                                           __HIP_MEMORY_SCOPE_AGENT);
      if (ra == 15u) {
#pragma unroll
        for (int k = 0; k < 16; ++k)
          __hip_atomic_store(&bar[k * 16], 0u, __ATOMIC_RELAXED,
                             __HIP_MEMORY_SCOPE_AGENT);
        __hip_atomic_store(bar + 256, 0u, __ATOMIC_RELAXED,
                           __HIP_MEMORY_SCOPE_AGENT);
        __builtin_amdgcn_s_waitcnt(0);
        __hip_atomic_store(gen, g + 1u, __ATOMIC_RELAXED,
                           __HIP_MEMORY_SCOPE_AGENT);
        pub = true;
      }
    }
    if (!pub) {
      unsigned t = 0;
      while (__hip_atomic_load(gen, __ATOMIC_RELAXED,
                               __HIP_MEMORY_SCOPE_AGENT) == g) {
        if (t < 64)
          __builtin_amdgcn_s_sleep(1);
        else
          __builtin_amdgcn_s_sleep(8);
        if (++t > (1u << 20)) break;  // escape hatch: fail, don't hang
      }
    }
  }
  __atomic_signal_fence(__ATOMIC_SEQ_CST);
  __syncthreads();
}

// hi/lo bf16 fragment from global X: lane holds row `row`, k = kb..kb+7.
__device__ __forceinline__ void conv_frag(const float* __restrict__ X, int row,
                                          int kb, v8s& h, v8s& l) {
  const float4* rp = (const float4*)(X + (size_t)row * DD + kb);
  float4 f0 = rp[0], f1 = rp[1];
  float f[8] = {f0.x, f0.y, f0.z, f0.w, f1.x, f1.y, f1.z, f1.w};
  union {
    v8s v;
    ushort u[8];
  } H, L;
#pragma unroll
  for (int j = 0; j < 8; ++j) {
    float fs = SCF * f[j];
    ushort hb = f2bf(fs);
    H.u[j] = hb;
    L.u[j] = f2bf(fs - bf2f(hb));
  }
  h = H.v;
  l = L.v;
}

// ---------------- setup kernels ----------------

__global__ void setup_zero(double* __restrict__ slots, int nsl,
                           unsigned* __restrict__ bar) {
  int i = blockIdx.x * 256 + threadIdx.x;
  int st = gridDim.x * 256;
  for (int k = i; k < nsl; k += st) slots[k] = 0.0;
  if (i < 512) bar[i] = 0u;
}

// stores NC2 * ||x||^2
__global__ void row_norms(const float* __restrict__ X, float* __restrict__ xx) {
  int i = blockIdx.x * blockDim.x + threadIdx.x;
  if (i < NN) {
    const float4* row = (const float4*)(X + (size_t)i * DD);
    float s = 0.f;
#pragma unroll
    for (int k = 0; k < DD / 4; ++k) {
      float4 v = row[k];
      s += v.x * v.x + v.y * v.y + v.z * v.z + v.w * v.w;
    }
    xx[i] = NC2 * s;
  }
}

// ---------------- matvec compute core (4 row-tiles / wave) ----------------
__device__ __forceinline__ void mv_compute(const v8s* ah, const v8s* al,
                                           const ushort (*Bh)[512],
                                           const ushort (*Bl)[512],
                                           const float* Wj, int lane,
                                           float racc[4][4]) {
  const int n = lane & 15;
  for (int t = 0; t < 16; ++t) {
    v8s bh = *(const v8s*)&Bh[t][lane * 8];
    v8s bl = *(const v8s*)&Bl[t][lane * 8];
    float wn = Wj[t * 16 + n];
#pragma unroll
    for (int rs = 0; rs < 4; ++rs) {
      v4f c = {0.f, 0.f, 0.f, 0.f};
      c = __builtin_amdgcn_mfma_f32_16x16x32_bf16(al[rs], bh, c, 0, 0, 0);
      c = __builtin_amdgcn_mfma_f32_16x16x32_bf16(ah[rs], bl, c, 0, 0, 0);
      c = __builtin_amdgcn_mfma_f32_16x16x32_bf16(ah[rs], bh, c, 0, 0, 0);
#pragma unroll
      for (int u = 0; u < 4; ++u)
        racc[rs][u] = fmaf(fast_exp2(c[u]), wn, racc[rs][u]);
    }
  }
}

// ---------------- persistent CG-CG kernel ----------------
// Grid 256 blocks x 1024 threads: 8 rowblocks (1024 rows) x 32 slices
// (256 cols). All CG vectors live in block-local LDS.

__global__ __launch_bounds__(1024, 4) void cg_persist(
    const float* __restrict__ Xtr, const float* __restrict__ Xte,
    const float* __restrict__ xx_tr, const float* __restrict__ xx_te,
    const float* __restrict__ y, float* __restrict__ qp0,
    float* __restrict__ qp1, double* __restrict__ rho_s,
    double* __restrict__ mu_s, unsigned* __restrict__ bar,
    float* __restrict__ out, int db) {
  __shared__ __align__(16) ushort Bh[16][512];
  __shared__ __align__(16) ushort Bl[16][512];
  __shared__ float Wj[256];
  __shared__ float Ebj[256];
  __shared__ float Erow[1024];
  __shared__ float Rrow[1024], Qrow[1024];
  __shared__ float Rcol[256], Qcol[256], Pcol[256], Xcol[256];
  __shared__ double sredq[16];
  __shared__ double sredr[16];
  __shared__ float s_ab[2];  // alpha, beta

  const int tid = threadIdx.x;
  const int lane = tid & 63;
  const int wid = tid >> 6;
  const int n = lane & 15, q4 = lane >> 4;
  const int rbi = blockIdx.x & 7;
  const int sli = blockIdx.x >> 3;
  const int rowbase = rbi * 1024;
  const int i0 = rowbase + wid * 64;
  const int jbase = sli * 256;

  // ---- stage B-slice into LDS once ----
  {
    int c = tid & 255;
    int j = jbase + c;
    int g = tid >> 8;
    int tile = c >> 4, cl = c & 15;
    const float4* rp = (const float4*)(Xtr + (size_t)j * DD);
    float4 f0 = rp[2 * g], f1 = rp[2 * g + 1];
    float f[8] = {f0.x, f0.y, f0.z, f0.w, f1.x, f1.y, f1.z, f1.w};
    union {
      ushort u[8];
      uint4 qq;
    } H, L;
#pragma unroll
    for (int e = 0; e < 8; ++e) {
      float fs = SCF * f[e];
      ushort hb = f2bf(fs);
      H.u[e] = hb;
      L.u[e] = f2bf(fs - bf2f(hb));
    }
    int ln = cl + 16 * g;
    *(uint4*)&Bh[tile][ln * 8] = H.qq;
    *(uint4*)&Bl[tile][ln * 8] = L.qq;
  }
  if (tid < 256) Ebj[tid] = fast_exp2(xx_tr[jbase + tid]);
  Erow[tid] = fast_exp2(xx_tr[rowbase + tid]);

  // ---- block-local CG state ----
  Rrow[tid] = y[rowbase + tid];
  Qrow[tid] = 0.f;
  if (tid < 256) {
    Rcol[tid] = y[jbase + tid];
    Qcol[tid] = 0.f;
    Pcol[tid] = 0.f;
    Xcol[tid] = 0.f;
  }

  // ---- A fragments in registers, converted once ----
  v8s ah[4], al[4];
#pragma unroll
  for (int rs = 0; rs < 4; ++rs)
    conv_frag(Xtr, i0 + rs * 16 + n, q4 * 8, ah[rs], al[rs]);

  double rho_old = 1.0, alpha_old = 1.0;  // wave-0 recurrence state
  __syncthreads();

  for (int it = 0; it < NITER; ++it) {
    float* qp = (db && (it & 1)) ? qp1 : qp0;

    // 1. matvec input: Wj = r_k[cols] * col exp factor
    if (tid < 256) Wj[tid] = Rcol[tid] * Ebj[tid];
    // 2. rho partial (slice-0 blocks): r.r over this rowblock
    if (sli == 0) {
      float rvv = Rrow[tid];
      double acc = wave_down_sum_d((double)rvv * (double)rvv);
      if (lane == 0) sredr[wid] = acc;
    }
    __syncthreads();
    if (sli == 0 && tid == 0) {
      double t = 0.0;
#pragma unroll
      for (int k3 = 0; k3 < 16; ++k3) t += sredr[k3];
      add_d(&rho_s[(size_t)it * 32 + rbi], t);
    }

    // 3. matvec on r
    float racc[4][4] = {};
    mv_compute(ah, al, Bh, Bl, Wj, lane, racc);
#pragma unroll
    for (int rs = 0; rs < 4; ++rs)
#pragma unroll
      for (int u = 0; u < 4; ++u) {
#pragma unroll
        for (int m = 1; m < 16; m <<= 1)
          racc[rs][u] += __shfl_xor(racc[rs][u], m, 64);
      }
    double cmu = 0.0;
    if (n == 0) {
#pragma unroll
      for (int rs = 0; rs < 4; ++rs)
#pragma unroll
        for (int u = 0; u < 4; ++u) {
          int lrow = wid * 64 + rs * 16 + q4 * 4 + u;
          float qc = racc[rs][u] * Erow[lrow];  // (K r)_row, this slice
          st_f(&qp[(size_t)sli * NN + rowbase + lrow], qc);
          cmu += (double)qc * (double)Rrow[lrow];  // r.Kr partial
        }
    }
    cmu = bfly64_d(cmu);
    if (lane == 0) sredq[wid] = cmu;
    __syncthreads();
    if (tid == 0) {
      double t = 0.0;
#pragma unroll
      for (int k3 = 0; k3 < 16; ++k3) t += sredq[k3];
      add_d(&mu_s[(size_t)it * 32 + (blockIdx.x & 31)], t);
    }

    gbarrier(bar);  // the ONE barrier: qp + rho + mu complete

    // 4. scalars via CG-CG recurrence (wave 0, then LDS broadcast)
    if (wid == 0) {
      double r1 = bfly32_d(ld_d(rho_s + (size_t)it * 32 + (lane & 31)));
      double m1 = bfly32_d(ld_d(mu_s + (size_t)it * 32 + (lane & 31)));
      double mu = m1 + (double)REGL * r1;  // r.(K+reg I)r
      double beta_d = (it == 0) ? 0.0 : r1 / rho_old;
      double alpha_d =
          (it == 0) ? r1 / mu : r1 / (mu - r1 * beta_d / alpha_old);
      rho_old = r1;
      alpha_old = alpha_d;
      if (lane == 0) {
        s_ab[0] = (float)alpha_d;
        s_ab[1] = (float)beta_d;
      }
    }
    __syncthreads();
    const float alpha = s_ab[0], beta = s_ab[1];

    // 5. gather w = K r (+reg r) at rows and cols; flat ascending slice
    //    order everywhere so replicated values stay bitwise identical.
    float wr;
    {
      const float* qb = qp + rowbase + tid;
      float s = 0.f;
#pragma unroll
      for (int s2 = 0; s2 < 32; ++s2) s += ld_f(qb + (size_t)s2 * NN);
      wr = fmaf(REGL, Rrow[tid], s);
    }
    float wc = 0.f;
    if (tid < 256) {
      const float* qb = qp + jbase + tid;
      float s = 0.f;
#pragma unroll
      for (int s2 = 0; s2 < 32; ++s2) s += ld_f(qb + (size_t)s2 * NN);
      wc = fmaf(REGL, Rcol[tid], s);
    }

    // 6. block-local updates: q = w + beta q; p = r + beta p;
    //    x += alpha p; r -= alpha q.
    {
      float qn = fmaf(beta, Qrow[tid], wr);
      Qrow[tid] = qn;
      Rrow[tid] = fmaf(-alpha, qn, Rrow[tid]);
    }
    if (tid < 256) {
      float qn = fmaf(beta, Qcol[tid], wc);
      Qcol[tid] = qn;
      float pn = fmaf(beta, Pcol[tid], Rcol[tid]);
      Pcol[tid] = pn;
      Xcol[tid] = fmaf(alpha, pn, Xcol[tid]);
      Rcol[tid] = fmaf(-alpha, qn, Rcol[tid]);
    }
    if (!db) gbarrier(bar);  // single-buffer: protect qp before next matvec
    // db=1: cross-thread Rrow reads next iter are covered by the loop-top
    // __syncthreads(); qp reuse is protected by the alternating buffer.
  }

  // ---- predict: out = K_test @ x, x = Xcol (block-local) ----
  {
    v8s th[4], tl[4];
#pragma unroll
    for (int rs = 0; rs < 4; ++rs)
      conv_frag(Xte, i0 + rs * 16 + n, q4 * 8, th[rs], tl[rs]);
    if (tid < 256) Wj[tid] = Xcol[tid] * Ebj[tid];
    Erow[tid] = fast_exp2(xx_te[rowbase + tid]);
    __syncthreads();
    float racc[4][4] = {};
    mv_compute(th, tl, Bh, Bl, Wj, lane, racc);
#pragma unroll
    for (int rs = 0; rs < 4; ++rs)
#pragma unroll
      for (int u = 0; u < 4; ++u) {
#pragma unroll
        for (int m = 1; m < 16; m <<= 1)
          racc[rs][u] += __shfl_xor(racc[rs][u], m, 64);
      }
    if (n == 0) {
#pragma unroll
      for (int rs = 0; rs < 4; ++rs)
#pragma unroll
        for (int u = 0; u < 4; ++u) {
          int lrow = wid * 64 + rs * 16 + q4 * 4 + u;
          st_f(&qp0[(size_t)sli * NN + rowbase + lrow],
               racc[rs][u] * Erow[lrow]);
        }
    }
    gbarrier(bar);
    if (sli == 0) {
      const float* qb = qp0 + rowbase + tid;
      float s = 0.f;
#pragma unroll
      for (int s2 = 0; s2 < 32; ++s2) s += ld_f(qb + (size_t)s2 * NN);
      out[rowbase + tid] = s;
    }
  }
}

// ---------------- launcher ----------------

extern "C" void kernel_launch(void* const* d_in, const int* in_sizes, int n_in,
                              void* d_out, int out_size, void* d_ws,
                              size_t ws_size, hipStream_t stream) {
  const float* X_train = (const float*)d_in[0];
  const float* y_train = (const float*)d_in[1];
  const float* X_test = (const float*)d_in[2];
  float* out = (float*)d_out;

  char* w = (char*)d_ws;
  size_t off = 0;
  float* xx_tr = (float*)(w + off); off += NN * 4;
  float* xx_te = (float*)(w + off); off += NN * 4;
  double* rho_s = (double*)(w + off); off += (size_t)NITER * 32 * 8;
  double* mu_s = (double*)(w + off); off += (size_t)NITER * 32 * 8;
  unsigned* bar = (unsigned*)(w + off); off += 2048;
  off = (off + 255) & ~(size_t)255;
  float* qp0 = (float*)(w + off); off += (size_t)32 * NN * 4;  // 1MB
  size_t need0 = off;
  float* qp1 = (float*)(w + off); off += (size_t)32 * NN * 4;  // 1MB
  size_t need1 = off;

  int db = (ws_size >= need1) ? 1 : 0;
  if (ws_size < need0) return;  // ~1.2MB; R11/R12 behavior implies available
  if (!db) qp1 = qp0;

  const int nslots = 2 * NITER * 32;
  setup_zero<<<32, 256, 0, stream>>>(rho_s, nslots, bar);
  row_norms<<<NN / 256, 256, 0, stream>>>(X_train, xx_tr);
  row_norms<<<NN / 256, 256, 0, stream>>>(X_test, xx_te);

  cg_persist<<<NBLK, 1024, 0, stream>>>(X_train, X_test, xx_tr, xx_te,
                                        y_train, qp0, qp1, rho_s, mu_s, bar,
                                        out, db);
}